// Round 9
// baseline (298.852 us; speedup 1.0000x reference)
//
#include <hip/hip_runtime.h>
#include <hip/hip_bf16.h>
#include <math.h>

typedef float  f32x4  __attribute__((ext_vector_type(4)));
typedef float  f32x16 __attribute__((ext_vector_type(16)));
typedef short  s16x8  __attribute__((ext_vector_type(8)));
typedef __bf16 bf16x8 __attribute__((ext_vector_type(8)));
typedef unsigned int u32;
typedef unsigned int u32x4 __attribute__((ext_vector_type(4)));
typedef unsigned short u16;
typedef unsigned long long u64;

#define DEVI static __device__ __forceinline__

#if defined(__has_builtin) && __has_builtin(__builtin_amdgcn_exp2f)
#define EXP2(x) __builtin_amdgcn_exp2f(x)
#else
#define EXP2(x) exp2f(x)
#endif

// one-instruction packed f32->bf16 RNE pair (v_cvt_pk_bf16_f32)
DEVI u32 cvtpk(float lo, float hi) {
  u32 r;
  asm("v_cvt_pk_bf16_f32 %0, %1, %2" : "=v"(r) : "v"(lo), "v"(hi));
  return r;
}

DEVI f32x4 mfma_bf16(s16x8 a, s16x8 b, f32x4 c) {
  return __builtin_amdgcn_mfma_f32_16x16x32_bf16(
      __builtin_bit_cast(bf16x8, a), __builtin_bit_cast(bf16x8, b), c, 0, 0, 0);
}

DEVI f32x16 mfma32(s16x8 a, s16x8 b, f32x16 c) {
  return __builtin_amdgcn_mfma_f32_32x32x16_bf16(
      __builtin_bit_cast(bf16x8, a), __builtin_bit_cast(bf16x8, b), c, 0, 0, 0);
}

DEVI void gload_lds16(const void* g, void* l) {
  __builtin_amdgcn_global_load_lds(
      (const __attribute__((address_space(1))) void*)g,
      (__attribute__((address_space(3))) void*)l, 16, 0, 0);
}

// ---------------------------------------------------------------------------
// Kernel 0: bit-pack KEEP bits (parallel: one word per wave, one load/lane).
// ---------------------------------------------------------------------------
__global__ __launch_bounds__(256)
void mask_pack(const int* __restrict__ mask, u64* __restrict__ mp) {
  const int t = threadIdx.x, lane = t & 63;
  const int gw = blockIdx.x * 4 + (t >> 6);
  const int kt = gw & 31, q = (gw >> 5) & 2047, b = gw >> 16;
  int mv = mask[((size_t)b * 2048 + q) * 2048 + kt * 64 + lane];
  u64 bits = __ballot(mv == 0);
  if (lane == 0) mp[((size_t)b * 32 + kt) * 2048 + q] = bits;
}

// ---------------------------------------------------------------------------
// Kernel 1: QKV projections (frozen).
// ---------------------------------------------------------------------------
__global__ __launch_bounds__(256, 2)
void qkv_proj(const float* __restrict__ xq, const float* __restrict__ xkv,
              const float* __restrict__ wq, const float* __restrict__ bq,
              const float* __restrict__ wk, const float* __restrict__ bk,
              const float* __restrict__ wv, const float* __restrict__ bv,
              u16* __restrict__ Qo, u16* __restrict__ Ko, u16* __restrict__ VTo)
{
  __shared__ __align__(16) char smem[128 * 272];
  char* lds_a = smem;
  char* lds_b = smem + 8192;

  const int t = threadIdx.x, lane = t & 63, w = t >> 6;
  const int z = blockIdx.z;
  const float* X  = (z == 0) ? xq : xkv;
  const float* W  = (z == 0) ? wq : (z == 1 ? wk : wv);
  const float* Bv = (z == 0) ? bq : (z == 1 ? bk : bv);

  const int m0 = blockIdx.x * 128, n0 = blockIdx.y * 128;
  const int wr = w >> 1, wc = w & 1, g = lane >> 4, q15 = lane & 15;
  const int srow = t >> 1, shalf = t & 1;

  f32x4 acc[4][4];
  #pragma unroll
  for (int i = 0; i < 4; ++i)
    #pragma unroll
    for (int j = 0; j < 4; ++j) acc[i][j] = (f32x4){0.f, 0.f, 0.f, 0.f};

  const float* gA = X + (size_t)(m0 + srow) * 512 + shalf * 16;
  const float* gB = W + (size_t)(n0 + srow) * 512 + shalf * 16;
  const int wbyte = srow * 64;
  const int sw = (srow & 3) << 4;

  #pragma unroll 1
  for (int kt = 0; kt < 16; ++kt) {
    float4 fa[4], fb[4];
    #pragma unroll
    for (int j = 0; j < 4; ++j) {
      fa[j] = *(const float4*)(gA + kt * 32 + j * 4);
      fb[j] = *(const float4*)(gB + kt * 32 + j * 4);
    }
    __syncthreads();
    const float* pfa = (const float*)fa;
    const float* pfb = (const float*)fb;
    #pragma unroll
    for (int half = 0; half < 2; ++half) {
      u32x4 wa, wb;
      #pragma unroll
      for (int e2 = 0; e2 < 4; ++e2) {
        wa[e2] = cvtpk(pfa[half * 8 + 2 * e2], pfa[half * 8 + 2 * e2 + 1]);
        wb[e2] = cvtpk(pfb[half * 8 + 2 * e2], pfb[half * 8 + 2 * e2 + 1]);
      }
      *(u32x4*)(lds_a + wbyte + ((shalf * 32 + half * 16) ^ sw)) = wa;
      *(u32x4*)(lds_b + wbyte + ((shalf * 32 + half * 16) ^ sw)) = wb;
    }
    __syncthreads();
    s16x8 afr[4], bfr[4];
    #pragma unroll
    for (int mi = 0; mi < 4; ++mi) {
      int row = wr * 64 + mi * 16 + q15;
      afr[mi] = *(const s16x8*)(lds_a + row * 64 + ((g * 16) ^ ((row & 3) << 4)));
    }
    #pragma unroll
    for (int ni = 0; ni < 4; ++ni) {
      int row = wc * 64 + ni * 16 + q15;
      bfr[ni] = *(const s16x8*)(lds_b + row * 64 + ((g * 16) ^ ((row & 3) << 4)));
    }
    #pragma unroll
    for (int mi = 0; mi < 4; ++mi)
      #pragma unroll
      for (int ni = 0; ni < 4; ++ni)
        acc[mi][ni] = mfma_bf16(afr[mi], bfr[ni], acc[mi][ni]);
  }

  float bias[4];
  #pragma unroll
  for (int ni = 0; ni < 4; ++ni) bias[ni] = Bv[n0 + wc * 64 + ni * 16 + q15];

  if (z < 2) {
    u16* Out = z ? Ko : Qo;
    const float scale = z ? 1.0f : 0.18033688011112042f;
    #pragma unroll
    for (int mi = 0; mi < 4; ++mi)
      #pragma unroll
      for (int ni = 0; ni < 4; ++ni)
        #pragma unroll
        for (int r = 0; r < 4; r += 2) {
          int m = m0 + wr * 64 + mi * 16 + g * 4 + r;
          int n = n0 + wc * 64 + ni * 16 + q15;
          u32 pk = cvtpk((acc[mi][ni][r] + bias[ni]) * scale,
                         (acc[mi][ni][r + 1] + bias[ni]) * scale);
          Out[(size_t)m * 512 + n]       = (u16)pk;
          Out[(size_t)(m + 1) * 512 + n] = (u16)(pk >> 16);
        }
  } else {
    __syncthreads();
    #pragma unroll
    for (int mi = 0; mi < 4; ++mi)
      #pragma unroll
      for (int ni = 0; ni < 4; ++ni)
        #pragma unroll
        for (int r = 0; r < 4; r += 2) {
          int ml = wr * 64 + mi * 16 + g * 4 + r;
          int nl = wc * 64 + ni * 16 + q15;
          *(u32*)(smem + nl * 272 + ml * 2) =
              cvtpk(acc[mi][ni][r] + bias[ni], acc[mi][ni][r + 1] + bias[ni]);
        }
    __syncthreads();
    const int b  = m0 >> 11;
    const int s0 = m0 & 2047;
    #pragma unroll
    for (int nn = 0; nn < 2; ++nn) {
      int n  = nn * 64 + (t >> 2);
      int q4 = t & 3;
      u16* dst = VTo + (size_t)(b * 512 + n0 + n) * 2048 + s0 + q4 * 32;
      #pragma unroll
      for (int jj = 0; jj < 4; ++jj)
        *(s16x8*)(dst + jj * 8) = *(const s16x8*)(smem + n * 272 + q4 * 64 + jj * 16);
    }
  }
}

// ---------------------------------------------------------------------------
// Kernel 2: fused flash attention — BARRIER-FREE wave-private pipeline.
// K: direct global->VGPR (E/O reg dbuf, 1-ahead).  V: per-wave private LDS
// (2x8KB dbuf, 2-ahead via global_load_lds).  Mask: 1-ahead reg.  Single
// counted vmcnt(28) per tile; no s_barrier -> waves drift into MFMA/VALU
// overlap.  No-max exp2 softmax, VALU row sums.
// grid.x = h + 8*b + 64*qt; block 128 = 2 waves x 64 q-rows.
// ---------------------------------------------------------------------------
DEVI void exp_pack(const f32x16& p0, const f32x16& p1, u64 kw, int hi,
                   u32* wds, float& lrun) {
  u64 kws = kw >> (hi * 4);
  u32 mm0 = (u32)kws, mm1 = (u32)(kws >> 32);
  float ls = 0.f;
  #pragma unroll
  for (int t2 = 0; t2 < 2; ++t2) {
    const u32 mmw = t2 ? mm1 : mm0;
    #pragma unroll
    for (int q2 = 0; q2 < 8; ++q2) {
      const int bp = 8 * (q2 >> 1) + 2 * (q2 & 1);
      float s0v = t2 ? p1[2 * q2] : p0[2 * q2];
      float s1v = t2 ? p1[2 * q2 + 1] : p0[2 * q2 + 1];
      float e0 = EXP2(s0v), e1 = EXP2(s1v);
      u32 k0 = (u32)((int)(mmw << (31 - bp)) >> 31);
      u32 k1 = (u32)((int)(mmw << (30 - bp)) >> 31);
      e0 = __builtin_bit_cast(float, __builtin_bit_cast(u32, e0) & k0);
      e1 = __builtin_bit_cast(float, __builtin_bit_cast(u32, e1) & k1);
      ls += e0; ls += e1;
      wds[t2 * 8 + q2] = cvtpk(e0, e1);
    }
  }
  lrun += ls;
}

DEVI void pv_accum(const u32* wa, const u32* wb, const char* vbase,
                   int l31, int hi, int swz,
                   f32x16& oA0, f32x16& oA1, f32x16& oB0, f32x16& oB1) {
  #pragma unroll
  for (int j = 0; j < 4; ++j) {
    const int ia = 2 * j, ib = 2 * j + 1;
    u32 a0 = wa[(ia >> 2) * 8 + 2 * (ia & 3)];
    u32 a1 = wa[(ia >> 2) * 8 + 2 * (ia & 3) + 1];
    u32 a2 = wa[(ib >> 2) * 8 + 2 * (ib & 3)];
    u32 a3 = wa[(ib >> 2) * 8 + 2 * (ib & 3) + 1];
    asm("v_permlane32_swap_b32 %0, %1" : "+v"(a0), "+v"(a2));
    asm("v_permlane32_swap_b32 %0, %1" : "+v"(a1), "+v"(a3));
    u32x4 awA = {a0, a1, a2, a3};
    s16x8 afA = __builtin_bit_cast(s16x8, awA);
    u32 b0 = wb[(ia >> 2) * 8 + 2 * (ia & 3)];
    u32 b1 = wb[(ia >> 2) * 8 + 2 * (ia & 3) + 1];
    u32 b2 = wb[(ib >> 2) * 8 + 2 * (ib & 3)];
    u32 b3 = wb[(ib >> 2) * 8 + 2 * (ib & 3) + 1];
    asm("v_permlane32_swap_b32 %0, %1" : "+v"(b0), "+v"(b2));
    asm("v_permlane32_swap_b32 %0, %1" : "+v"(b1), "+v"(b3));
    u32x4 awB = {b0, b1, b2, b3};
    s16x8 afB = __builtin_bit_cast(s16x8, awB);
    s16x8 v0 = *(const s16x8*)(vbase + l31 * 128        + ((j * 32 + hi * 16) ^ swz));
    s16x8 v1 = *(const s16x8*)(vbase + (l31 + 32) * 128 + ((j * 32 + hi * 16) ^ swz));
    oA0 = mfma32(afA, v0, oA0);
    oA1 = mfma32(afA, v1, oA1);
    oB0 = mfma32(afB, v0, oB0);
    oB1 = mfma32(afB, v1, oB1);
  }
}

__global__ __launch_bounds__(128, 2)
void attn_fwd(const u16* __restrict__ Q, const u16* __restrict__ K,
              const u16* __restrict__ VT, const u64* __restrict__ MP,
              float* __restrict__ out)
{
  __shared__ __align__(16) char lds_v[2][2][8192];  // [wave][buf][d64*kv64]

  const int bid = blockIdx.x;
  const int h = bid & 7, b = (bid >> 3) & 7, qt = bid >> 6;
  const int t = threadIdx.x, lane = t & 63, w = t >> 6;   // w in {0,1}
  const int l31 = lane & 31, hi = lane >> 5;
  const int qbase = qt * 128 + w * 64;
  const int swz = (l31 & 7) << 4;

  s16x8 qfa[4], qfb[4];
  #pragma unroll
  for (int j = 0; j < 4; ++j) {
    qfa[j] = *(const s16x8*)(Q + (size_t)(b * 2048 + qbase + l31) * 512
                               + h * 64 + j * 16 + hi * 8);
    qfb[j] = *(const s16x8*)(Q + (size_t)(b * 2048 + qbase + 32 + l31) * 512
                               + h * 64 + j * 16 + hi * 8);
  }
  asm volatile("" ::: "memory");

  f32x16 oA0 = {0.f,0.f,0.f,0.f,0.f,0.f,0.f,0.f,0.f,0.f,0.f,0.f,0.f,0.f,0.f,0.f};
  f32x16 oA1 = oA0, oB0 = oA0, oB1 = oA0;
  const f32x16 ZZ = oA0;
  float lrunA = 0.f, lrunB = 0.f;

  // K direct-load bases (bytes): rows l31 / l31+32, tile 0
  const char* kR0 = (const char*)K + ((size_t)(b * 2048 + l31) * 512 + h * 64) * 2 + hi * 16;
  const char* kR1 = kR0 + 32 * 1024;
  // V stage source (u16): rows d = i*8 + (lane>>3), pre-swizzled chunk
  const int sx = ((lane & 7) ^ (lane >> 3)) * 8;
  const u16* vB = VT + (size_t)(b * 512 + h * 64 + (lane >> 3)) * 2048 + sx;
  // mask ptrs
  const u64* mpA = MP + (size_t)b * 32 * 2048 + qbase + l31;
  const u64* mpB = mpA + 32;

  s16x8 kfE[8], kfO[8];
  u64 pmEA, pmEB, pmOA, pmOB;

  // ---- prologue: V(0), K(0), M(0), V(1) ----
  #pragma unroll
  for (int i = 0; i < 8; ++i) gload_lds16(vB + i * 16384, &lds_v[w][0][i * 1024]);
  asm volatile("" ::: "memory");
  #pragma unroll
  for (int j = 0; j < 4; ++j) {
    kfE[j]     = *(const s16x8*)(kR0 + j * 32);
    kfE[4 + j] = *(const s16x8*)(kR1 + j * 32);
  }
  kR0 += 65536; kR1 += 65536;
  asm volatile("" ::: "memory");
  pmEA = mpA[0]; pmEB = mpB[0]; mpA += 2048; mpB += 2048;
  asm volatile("" ::: "memory");
  #pragma unroll
  for (int i = 0; i < 8; ++i) gload_lds16(vB + 64 + i * 16384, &lds_v[w][1][i * 1024]);
  vB += 128;
  asm volatile("" ::: "memory");

  // body: QK(t) | issue K(t+1) | issue M(t+1) | exp(t) | vmcnt | PV(t) | issue V(t+2)
#define BODY(KF, KFN, PMA_, PMB_, PMNA_, PMNB_, BUF, DO_K, DO_M, DO_V, WAITASM) do { \
    f32x16 pa0 = ZZ, pa1 = ZZ, pb0 = ZZ, pb1 = ZZ;                                   \
    _Pragma("unroll")                                                                 \
    for (int j = 0; j < 4; ++j) {                                                     \
      pa0 = mfma32(KF[j],     qfa[j], pa0);                                           \
      pa1 = mfma32(KF[4 + j], qfa[j], pa1);                                           \
      pb0 = mfma32(KF[j],     qfb[j], pb0);                                           \
      pb1 = mfma32(KF[4 + j], qfb[j], pb1);                                           \
    }                                                                                 \
    if (DO_K) {                                                                       \
      _Pragma("unroll")                                                               \
      for (int j = 0; j < 4; ++j) {                                                   \
        KFN[j]     = *(const s16x8*)(kR0 + j * 32);                                   \
        KFN[4 + j] = *(const s16x8*)(kR1 + j * 32);                                   \
      }                                                                               \
      kR0 += 65536; kR1 += 65536;                                                     \
      asm volatile("" ::: "memory");                                                  \
    }                                                                                 \
    if (DO_M) {                                                                       \
      PMNA_ = mpA[0]; PMNB_ = mpB[0]; mpA += 2048; mpB += 2048;                       \
      asm volatile("" ::: "memory");                                                  \
    }                                                                                 \
    u32 wa[16], wb[16];                                                               \
    exp_pack(pa0, pa1, PMA_, hi, wa, lrunA);                                          \
    exp_pack(pb0, pb1, PMB_, hi, wb, lrunB);                                          \
    asm volatile("s_waitcnt " WAITASM ::: "memory");                                  \
    pv_accum(wa, wb, &lds_v[w][BUF][0], l31, hi, swz, oA0, oA1, oB0, oB1);            \
    asm volatile("s_waitcnt lgkmcnt(0)" ::: "memory");                                \
    __builtin_amdgcn_sched_barrier(0);                                                \
    if (DO_V) {                                                                       \
      _Pragma("unroll")                                                               \
      for (int i = 0; i < 8; ++i) gload_lds16(vB + i * 16384, &lds_v[w][BUF][i * 1024]); \
      vB += 64;                                                                       \
      asm volatile("" ::: "memory");                                                  \
    }                                                                                 \
  } while (0)

  #pragma unroll 1
  for (int kt2 = 0; kt2 < 15; ++kt2) {     // bodies 0..29 (steady state)
    BODY(kfE, kfO, pmEA, pmEB, pmOA, pmOB, 0, 1, 1, 1, "vmcnt(28)");
    BODY(kfO, kfE, pmOA, pmOB, pmEA, pmEB, 1, 1, 1, 1, "vmcnt(28)");
  }
  // body 30: issues K(31)/M(31), no V(32)
  BODY(kfE, kfO, pmEA, pmEB, pmOA, pmOB, 0, 1, 1, 0, "vmcnt(28)");
  // body 31: no issues
  BODY(kfO, kfE, pmOA, pmOB, pmEA, pmEB, 1, 0, 0, 0, "vmcnt(10)");
#undef BODY

  // ---- epilogue: lane^32 halves hold disjoint kv -> full row sums ----
  lrunA += __shfl_xor(lrunA, 32);
  lrunB += __shfl_xor(lrunB, 32);
  const float rqA = 1.0f / lrunA;
  const float rqB = 1.0f / lrunB;
  #pragma unroll
  for (int reg = 0; reg < 16; ++reg) {
    const int ql = (reg & 3) + 8 * (reg >> 2) + 4 * hi;
    const float liA = __shfl(rqA, ql);
    const float liB = __shfl(rqB, ql);
    float* po = out + (size_t)(b * 2048 + qbase + ql) * 512 + h * 64 + l31;
    po[0]  = oA0[reg] * liA;
    po[32] = oA1[reg] * liA;
    float* po2 = po + (size_t)32 * 512;
    po2[0]  = oB0[reg] * liB;
    po2[32] = oB1[reg] * liB;
  }
}

extern "C" void kernel_launch(void* const* d_in, const int* in_sizes, int n_in,
                              void* d_out, int out_size, void* d_ws, size_t ws_size,
                              hipStream_t stream) {
  const float* xq  = (const float*)d_in[0];
  const float* xkv = (const float*)d_in[1];
  const int*   msk = (const int*)d_in[2];
  const float* wq  = (const float*)d_in[3];
  const float* bq  = (const float*)d_in[4];
  const float* wk  = (const float*)d_in[5];
  const float* bk  = (const float*)d_in[6];
  const float* wv  = (const float*)d_in[7];
  const float* bv  = (const float*)d_in[8];

  u16* Qw = (u16*)d_ws;                          // [16384][512] bf16 (x 0.1803)
  u16* Kw = Qw + (size_t)16384 * 512;            // [16384][512] bf16
  u16* VT = Kw + (size_t)16384 * 512;            // [4096][2048] bf16 (V^T)
  u64* MP = (u64*)(VT + (size_t)4096 * 2048);    // [8][32][2048] packed keep bits

  mask_pack<<<dim3(131072), 256, 0, stream>>>(msk, MP);
  qkv_proj<<<dim3(128, 4, 3), 256, 0, stream>>>(xq, xkv, wq, bq, wk, bk, wv, bv,
                                                Qw, Kw, VT);
  attn_fwd<<<dim3(1024), 128, 0, stream>>>(Qw, Kw, VT, MP, (float*)d_out);
}

// Round 10
// 219.040 us; speedup vs baseline: 1.3644x; 1.3644x over previous
//
#include <hip/hip_runtime.h>
#include <hip/hip_bf16.h>
#include <math.h>

typedef float  f32x4  __attribute__((ext_vector_type(4)));
typedef float  f32x16 __attribute__((ext_vector_type(16)));
typedef short  s16x8  __attribute__((ext_vector_type(8)));
typedef __bf16 bf16x8 __attribute__((ext_vector_type(8)));
typedef unsigned int u32;
typedef unsigned int u32x4 __attribute__((ext_vector_type(4)));
typedef unsigned short u16;
typedef unsigned long long u64;

#define DEVI static __device__ __forceinline__

#if defined(__has_builtin) && __has_builtin(__builtin_amdgcn_exp2f)
#define EXP2(x) __builtin_amdgcn_exp2f(x)
#else
#define EXP2(x) exp2f(x)
#endif

// one-instruction packed f32->bf16 RNE pair (v_cvt_pk_bf16_f32)
DEVI u32 cvtpk(float lo, float hi) {
  u32 r;
  asm("v_cvt_pk_bf16_f32 %0, %1, %2" : "=v"(r) : "v"(lo), "v"(hi));
  return r;
}

DEVI f32x4 mfma_bf16(s16x8 a, s16x8 b, f32x4 c) {
  return __builtin_amdgcn_mfma_f32_16x16x32_bf16(
      __builtin_bit_cast(bf16x8, a), __builtin_bit_cast(bf16x8, b), c, 0, 0, 0);
}

DEVI f32x16 mfma32(s16x8 a, s16x8 b, f32x16 c) {
  return __builtin_amdgcn_mfma_f32_32x32x16_bf16(
      __builtin_bit_cast(bf16x8, a), __builtin_bit_cast(bf16x8, b), c, 0, 0, 0);
}

DEVI void gload_lds16(const void* g, void* l) {
  __builtin_amdgcn_global_load_lds(
      (const __attribute__((address_space(1))) void*)g,
      (__attribute__((address_space(3))) void*)l, 16, 0, 0);
}

// ---------------------------------------------------------------------------
// Kernel 0: bit-pack KEEP bits.  8192 blocks x 4 waves x 16 words, 2-deep
// load-ahead (vs 131072 tiny blocks: same BW floor, far less dispatch).
// word (b,kt,q): bit l == 1  iff  kv = kt*64+l is KEPT (mask == 0).
// ---------------------------------------------------------------------------
__global__ __launch_bounds__(256)
void mask_pack(const int* __restrict__ mask, u64* __restrict__ mp) {
  const int t = threadIdx.x, lane = t & 63;
  const u32 gw = blockIdx.x * 4 + (t >> 6);       // 32768 waves
  const u32 W0 = gw * 16;                         // 16 consecutive words (q-adjacent)
  #define MSRC(W) ((((size_t)((W) >> 16) * 2048 + ((W) & 2047u)) * 2048) \
                   + (((W) >> 11) & 31u) * 64 + lane)
  int c0 = mask[MSRC(W0)];
  int c1 = mask[MSRC(W0 + 1)];
  #pragma unroll 4
  for (u32 k = 0; k < 16; ++k) {
    u64 bits = __ballot(c0 == 0);
    if (lane == 0) mp[W0 + k] = bits;
    c0 = c1;
    if (k + 2 < 16) c1 = mask[MSRC(W0 + k + 2)];
  }
  #undef MSRC
}

// ---------------------------------------------------------------------------
// Kernel 1: QKV projections (frozen this round — to be measured directly).
// ---------------------------------------------------------------------------
__global__ __launch_bounds__(256, 2)
void qkv_proj(const float* __restrict__ xq, const float* __restrict__ xkv,
              const float* __restrict__ wq, const float* __restrict__ bq,
              const float* __restrict__ wk, const float* __restrict__ bk,
              const float* __restrict__ wv, const float* __restrict__ bv,
              u16* __restrict__ Qo, u16* __restrict__ Ko, u16* __restrict__ VTo)
{
  __shared__ __align__(16) char smem[128 * 272];
  char* lds_a = smem;
  char* lds_b = smem + 8192;

  const int t = threadIdx.x, lane = t & 63, w = t >> 6;
  const int z = blockIdx.z;
  const float* X  = (z == 0) ? xq : xkv;
  const float* W  = (z == 0) ? wq : (z == 1 ? wk : wv);
  const float* Bv = (z == 0) ? bq : (z == 1 ? bk : bv);

  const int m0 = blockIdx.x * 128, n0 = blockIdx.y * 128;
  const int wr = w >> 1, wc = w & 1, g = lane >> 4, q15 = lane & 15;
  const int srow = t >> 1, shalf = t & 1;

  f32x4 acc[4][4];
  #pragma unroll
  for (int i = 0; i < 4; ++i)
    #pragma unroll
    for (int j = 0; j < 4; ++j) acc[i][j] = (f32x4){0.f, 0.f, 0.f, 0.f};

  const float* gA = X + (size_t)(m0 + srow) * 512 + shalf * 16;
  const float* gB = W + (size_t)(n0 + srow) * 512 + shalf * 16;
  const int wbyte = srow * 64;
  const int sw = (srow & 3) << 4;

  #pragma unroll 1
  for (int kt = 0; kt < 16; ++kt) {
    float4 fa[4], fb[4];
    #pragma unroll
    for (int j = 0; j < 4; ++j) {
      fa[j] = *(const float4*)(gA + kt * 32 + j * 4);
      fb[j] = *(const float4*)(gB + kt * 32 + j * 4);
    }
    __syncthreads();
    const float* pfa = (const float*)fa;
    const float* pfb = (const float*)fb;
    #pragma unroll
    for (int half = 0; half < 2; ++half) {
      u32x4 wa, wb;
      #pragma unroll
      for (int e2 = 0; e2 < 4; ++e2) {
        wa[e2] = cvtpk(pfa[half * 8 + 2 * e2], pfa[half * 8 + 2 * e2 + 1]);
        wb[e2] = cvtpk(pfb[half * 8 + 2 * e2], pfb[half * 8 + 2 * e2 + 1]);
      }
      *(u32x4*)(lds_a + wbyte + ((shalf * 32 + half * 16) ^ sw)) = wa;
      *(u32x4*)(lds_b + wbyte + ((shalf * 32 + half * 16) ^ sw)) = wb;
    }
    __syncthreads();
    s16x8 afr[4], bfr[4];
    #pragma unroll
    for (int mi = 0; mi < 4; ++mi) {
      int row = wr * 64 + mi * 16 + q15;
      afr[mi] = *(const s16x8*)(lds_a + row * 64 + ((g * 16) ^ ((row & 3) << 4)));
    }
    #pragma unroll
    for (int ni = 0; ni < 4; ++ni) {
      int row = wc * 64 + ni * 16 + q15;
      bfr[ni] = *(const s16x8*)(lds_b + row * 64 + ((g * 16) ^ ((row & 3) << 4)));
    }
    #pragma unroll
    for (int mi = 0; mi < 4; ++mi)
      #pragma unroll
      for (int ni = 0; ni < 4; ++ni)
        acc[mi][ni] = mfma_bf16(afr[mi], bfr[ni], acc[mi][ni]);
  }

  float bias[4];
  #pragma unroll
  for (int ni = 0; ni < 4; ++ni) bias[ni] = Bv[n0 + wc * 64 + ni * 16 + q15];

  if (z < 2) {
    u16* Out = z ? Ko : Qo;
    const float scale = z ? 1.0f : 0.18033688011112042f;
    #pragma unroll
    for (int mi = 0; mi < 4; ++mi)
      #pragma unroll
      for (int ni = 0; ni < 4; ++ni)
        #pragma unroll
        for (int r = 0; r < 4; r += 2) {
          int m = m0 + wr * 64 + mi * 16 + g * 4 + r;
          int n = n0 + wc * 64 + ni * 16 + q15;
          u32 pk = cvtpk((acc[mi][ni][r] + bias[ni]) * scale,
                         (acc[mi][ni][r + 1] + bias[ni]) * scale);
          Out[(size_t)m * 512 + n]       = (u16)pk;
          Out[(size_t)(m + 1) * 512 + n] = (u16)(pk >> 16);
        }
  } else {
    __syncthreads();
    #pragma unroll
    for (int mi = 0; mi < 4; ++mi)
      #pragma unroll
      for (int ni = 0; ni < 4; ++ni)
        #pragma unroll
        for (int r = 0; r < 4; r += 2) {
          int ml = wr * 64 + mi * 16 + g * 4 + r;
          int nl = wc * 64 + ni * 16 + q15;
          *(u32*)(smem + nl * 272 + ml * 2) =
              cvtpk(acc[mi][ni][r] + bias[ni], acc[mi][ni][r + 1] + bias[ni]);
        }
    __syncthreads();
    const int b  = m0 >> 11;
    const int s0 = m0 & 2047;
    #pragma unroll
    for (int nn = 0; nn < 2; ++nn) {
      int n  = nn * 64 + (t >> 2);
      int q4 = t & 3;
      u16* dst = VTo + (size_t)(b * 512 + n0 + n) * 2048 + s0 + q4 * 32;
      #pragma unroll
      for (int jj = 0; jj < 4; ++jj)
        *(s16x8*)(dst + jj * 8) = *(const s16x8*)(smem + n * 272 + q4 * 64 + jj * 16);
    }
  }
}

// ---------------------------------------------------------------------------
// Kernel 2: fused flash attention — R7 form (4 waves x 32q, KVBLK 64, LDS
// K/V dbuf) with SINGLE barrier per iter (R8-validated pattern: vmcnt(0)+
// lgkm(0) at top is free since stage(t) was issued a full iter earlier) and
// setprio around MFMA clusters.  No-max exp2 softmax, ones-MFMA row sums.
// grid.x = h + 8*b + 64*qt; block 256 = 4 waves x 32 q-rows.
// ---------------------------------------------------------------------------
__global__ __launch_bounds__(256, 2)
void attn_fwd(const u16* __restrict__ Q, const u16* __restrict__ K,
              const u16* __restrict__ VT, const u64* __restrict__ MP,
              float* __restrict__ out)
{
  __shared__ __align__(16) char lds_k[2][8192];  // [kv 64][d 64] bf16, swizzled
  __shared__ __align__(16) char lds_v[2][8192];  // [d 64][kv 64] bf16, swizzled

  const int bid = blockIdx.x;
  const int h = bid & 7, b = (bid >> 3) & 7, qt = bid >> 6;
  const int t = threadIdx.x, lane = t & 63, w = t >> 6;
  const int l31 = lane & 31, hi = lane >> 5;
  const int qbase = qt * 128 + w * 32;
  const int swz = (l31 & 7) << 4;

  // Q B-frags (pre-scaled by 0.125*log2e): col=q=l31, k(d) = j*16 + 8*hi + e
  s16x8 qf[4];
  #pragma unroll
  for (int j = 0; j < 4; ++j)
    qf[j] = *(const s16x8*)(Q + (size_t)(b * 2048 + qbase + l31) * 512
                              + h * 64 + j * 16 + hi * 8);
  asm volatile("" ::: "memory");        // pin qf loads before STAGE(0)

  f32x16 o0 = {0.f,0.f,0.f,0.f,0.f,0.f,0.f,0.f,0.f,0.f,0.f,0.f,0.f,0.f,0.f,0.f};
  f32x16 o1 = o0, o2 = o0;
  const f32x16 ZZ = o0;
  const s16x8 onesf = {0x3F80,0x3F80,0x3F80,0x3F80,0x3F80,0x3F80,0x3F80,0x3F80};

  const int srow8 = lane >> 3, slot = lane & 7;
  const int rl0 = w * 16 + srow8, rl1 = rl0 + 8;

  // loop-carried staging pointers
  const u16* kP0 = K + (size_t)(b * 2048 + rl0) * 512 + h * 64 + (slot ^ (rl0 & 7)) * 8;
  const u16* kP1 = K + (size_t)(b * 2048 + rl1) * 512 + h * 64 + (slot ^ (rl1 & 7)) * 8;
  const u16* vP0 = VT + (size_t)(b * 512 + h * 64 + rl0) * 2048 + (slot ^ (rl0 & 7)) * 8;
  const u16* vP1 = VT + (size_t)(b * 512 + h * 64 + rl1) * 2048 + (slot ^ (rl1 & 7)) * 8;
  const u64* mpP = MP + (size_t)b * 32 * 2048 + qbase + l31;

  // prologue: stage tile 0 into buf 0, prefetch mask word 0
  gload_lds16(kP0, &lds_k[0][w * 2048]);
  gload_lds16(vP0, &lds_v[0][w * 2048]);
  gload_lds16(kP1, &lds_k[0][w * 2048 + 1024]);
  gload_lds16(vP1, &lds_v[0][w * 2048 + 1024]);
  asm volatile("" ::: "memory");
  u64 pm = *mpP;

  #pragma unroll 1
  for (int kt = 0; kt < 32; ++kt) {
    const int cur = kt & 1;
    const u64 kw = pm;
    // stage(kt)/mask(kt) were issued a full iteration ago -> vmcnt(0) is free;
    // lgkm(0) covers my ds_reads of buf cur^1; barrier releases the swap.
    asm volatile("s_waitcnt vmcnt(0) lgkmcnt(0)" ::: "memory");
    __builtin_amdgcn_sched_barrier(0);
    asm volatile("s_barrier" ::: "memory");
    if (kt + 1 < 32) {
      kP0 += 32768; kP1 += 32768; vP0 += 64; vP1 += 64; mpP += 2048;
      gload_lds16(kP0, &lds_k[cur ^ 1][w * 2048]);
      gload_lds16(vP0, &lds_v[cur ^ 1][w * 2048]);
      gload_lds16(kP1, &lds_k[cur ^ 1][w * 2048 + 1024]);
      gload_lds16(vP1, &lds_v[cur ^ 1][w * 2048 + 1024]);
      asm volatile("" ::: "memory");
      pm = mpP[0];
    }

    // ---- S^T = K * Q^T over d=64 (4 mfma per kv-32 tile) ----
    f32x16 p0 = ZZ, p1 = ZZ;
    __builtin_amdgcn_s_setprio(1);
    #pragma unroll
    for (int j = 0; j < 4; ++j) {
      s16x8 a0 = *(const s16x8*)(&lds_k[cur][ l31       * 128 + ((j * 32 + hi * 16) ^ swz)]);
      s16x8 a1 = *(const s16x8*)(&lds_k[cur][(l31 + 32) * 128 + ((j * 32 + hi * 16) ^ swz)]);
      p0 = mfma32(a0, qf[j], p0);
      p1 = mfma32(a1, qf[j], p1);
    }
    __builtin_amdgcn_s_setprio(0);

    // ---- masked exp2 -> packed bf16 words ----
    // own kv of word (t2,q2): 32*t2 + 8*(q2>>1) + 2*(q2&1) + 4*hi (+0/+1)
    u64 kws = kw >> (hi * 4);
    u32 mm0 = (u32)kws, mm1 = (u32)(kws >> 32);
    u32 wds[16];
    #pragma unroll
    for (int t2 = 0; t2 < 2; ++t2) {
      const u32 mmw = t2 ? mm1 : mm0;
      #pragma unroll
      for (int q2 = 0; q2 < 8; ++q2) {
        const int bp = 8 * (q2 >> 1) + 2 * (q2 & 1);
        float s0v = t2 ? p1[2 * q2] : p0[2 * q2];
        float s1v = t2 ? p1[2 * q2 + 1] : p0[2 * q2 + 1];
        float e0 = EXP2(s0v), e1 = EXP2(s1v);
        u32 k0 = (u32)((int)(mmw << (31 - bp)) >> 31);
        u32 k1 = (u32)((int)(mmw << (30 - bp)) >> 31);
        e0 = __builtin_bit_cast(float, __builtin_bit_cast(u32, e0) & k0);
        e1 = __builtin_bit_cast(float, __builtin_bit_cast(u32, e1) & k1);
        wds[t2 * 8 + q2] = cvtpk(e0, e1);
      }
    }

    // ---- PV + ones-column row sums ----
    __builtin_amdgcn_s_setprio(1);
    #pragma unroll
    for (int j = 0; j < 4; ++j) {
      const int ia = 2 * j, ib = 2 * j + 1;
      u32 wa0 = wds[(ia >> 2) * 8 + 2 * (ia & 3)];
      u32 wa1 = wds[(ia >> 2) * 8 + 2 * (ia & 3) + 1];
      u32 wb0 = wds[(ib >> 2) * 8 + 2 * (ib & 3)];
      u32 wb1 = wds[(ib >> 2) * 8 + 2 * (ib & 3) + 1];
      asm("v_permlane32_swap_b32 %0, %1" : "+v"(wa0), "+v"(wb0));
      asm("v_permlane32_swap_b32 %0, %1" : "+v"(wa1), "+v"(wb1));
      u32x4 aw = {wa0, wa1, wb0, wb1};
      s16x8 af = __builtin_bit_cast(s16x8, aw);
      s16x8 v0 = *(const s16x8*)(&lds_v[cur][ l31       * 128 + ((j * 32 + hi * 16) ^ swz)]);
      s16x8 v1 = *(const s16x8*)(&lds_v[cur][(l31 + 32) * 128 + ((j * 32 + hi * 16) ^ swz)]);
      o0 = mfma32(af, v0, o0);
      o1 = mfma32(af, v1, o1);
      o2 = mfma32(af, onesf, o2);
    }
    __builtin_amdgcn_s_setprio(0);
  }

  // ---- epilogue: o2[reg] IS the row denominator for o0/o1[reg] ----
  #pragma unroll
  for (int reg = 0; reg < 16; ++reg) {
    const int ql = (reg & 3) + 8 * (reg >> 2) + 4 * hi;
    const float linv = 1.0f / o2[reg];
    float* po = out + (size_t)(b * 2048 + qbase + ql) * 512 + h * 64 + l31;
    po[0]  = o0[reg] * linv;
    po[32] = o1[reg] * linv;
  }
}

extern "C" void kernel_launch(void* const* d_in, const int* in_sizes, int n_in,
                              void* d_out, int out_size, void* d_ws, size_t ws_size,
                              hipStream_t stream) {
  const float* xq  = (const float*)d_in[0];
  const float* xkv = (const float*)d_in[1];
  const int*   msk = (const int*)d_in[2];
  const float* wq  = (const float*)d_in[3];
  const float* bq  = (const float*)d_in[4];
  const float* wk  = (const float*)d_in[5];
  const float* bk  = (const float*)d_in[6];
  const float* wv  = (const float*)d_in[7];
  const float* bv  = (const float*)d_in[8];

  u16* Qw = (u16*)d_ws;                          // [16384][512] bf16 (x 0.1803)
  u16* Kw = Qw + (size_t)16384 * 512;            // [16384][512] bf16
  u16* VT = Kw + (size_t)16384 * 512;            // [4096][2048] bf16 (V^T)
  u64* MP = (u64*)(VT + (size_t)4096 * 2048);    // [8][32][2048] packed keep bits

  mask_pack<<<dim3(8192), 256, 0, stream>>>(msk, MP);
  qkv_proj<<<dim3(128, 4, 3), 256, 0, stream>>>(xq, xkv, wq, bq, wk, bk, wv, bv,
                                                Qw, Kw, VT);
  attn_fwd<<<dim3(1024), 256, 0, stream>>>(Qw, Kw, VT, MP, (float*)d_out);
}

// Round 11
// 200.235 us; speedup vs baseline: 1.4925x; 1.0939x over previous
//
#include <hip/hip_runtime.h>
#include <hip/hip_bf16.h>
#include <math.h>

typedef float  f32x4  __attribute__((ext_vector_type(4)));
typedef float  f32x16 __attribute__((ext_vector_type(16)));
typedef short  s16x8  __attribute__((ext_vector_type(8)));
typedef __bf16 bf16x8 __attribute__((ext_vector_type(8)));
typedef unsigned int u32;
typedef unsigned int u32x4 __attribute__((ext_vector_type(4)));
typedef unsigned short u16;
typedef unsigned long long u64;

#define DEVI static __device__ __forceinline__

#if defined(__has_builtin) && __has_builtin(__builtin_amdgcn_exp2f)
#define EXP2(x) __builtin_amdgcn_exp2f(x)
#else
#define EXP2(x) exp2f(x)
#endif

// one-instruction packed f32->bf16 RNE pair (v_cvt_pk_bf16_f32)
DEVI u32 cvtpk(float lo, float hi) {
  u32 r;
  asm("v_cvt_pk_bf16_f32 %0, %1, %2" : "=v"(r) : "v"(lo), "v"(hi));
  return r;
}

DEVI f32x4 mfma_bf16(s16x8 a, s16x8 b, f32x4 c) {
  return __builtin_amdgcn_mfma_f32_16x16x32_bf16(
      __builtin_bit_cast(bf16x8, a), __builtin_bit_cast(bf16x8, b), c, 0, 0, 0);
}

DEVI f32x16 mfma32(s16x8 a, s16x8 b, f32x16 c) {
  return __builtin_amdgcn_mfma_f32_32x32x16_bf16(
      __builtin_bit_cast(bf16x8, a), __builtin_bit_cast(bf16x8, b), c, 0, 0, 0);
}

DEVI void gload_lds16(const void* g, void* l) {
  __builtin_amdgcn_global_load_lds(
      (const __attribute__((address_space(1))) void*)g,
      (__attribute__((address_space(3))) void*)l, 16, 0, 0);
}

// ---------------------------------------------------------------------------
// Kernel 0: blocks < 8192: bit-pack KEEP bits (16 words/wave, 2-deep ahead).
//           blocks >= 8192 (192): cast W{q,k,v} fp32 -> bf16 into Wbf.
// ---------------------------------------------------------------------------
__global__ __launch_bounds__(256)
void mask_pack(const int* __restrict__ mask, u64* __restrict__ mp,
               const float* __restrict__ wq, const float* __restrict__ wk,
               const float* __restrict__ wv, u16* __restrict__ Wbf) {
  const int t = threadIdx.x, lane = t & 63;
  if (blockIdx.x >= 8192) {             // ---- W cast: 192 blocks x 4096 elems
    const u32 blk = blockIdx.x - 8192;
    const u32 g0 = blk * 4096 + (u32)t * 16;
    const u32 mtx = g0 >> 18;           // 64 blocks per matrix
    const float* src = (mtx == 0) ? wq : (mtx == 1 ? wk : wv);
    const u32 idx = g0 & 262143u;
    #pragma unroll
    for (int i = 0; i < 2; ++i) {
      f32x4 v0 = *(const f32x4*)(src + idx + i * 8);
      f32x4 v1 = *(const f32x4*)(src + idx + i * 8 + 4);
      u32x4 pk;
      pk[0] = cvtpk(v0[0], v0[1]); pk[1] = cvtpk(v0[2], v0[3]);
      pk[2] = cvtpk(v1[0], v1[1]); pk[3] = cvtpk(v1[2], v1[3]);
      *(u32x4*)(Wbf + (size_t)mtx * 262144 + idx + i * 8) = pk;
    }
    return;
  }
  const u32 gw = blockIdx.x * 4 + (t >> 6);
  const u32 W0 = gw * 16;
  #define MSRC(W) ((((size_t)((W) >> 16) * 2048 + ((W) & 2047u)) * 2048) \
                   + (((W) >> 11) & 31u) * 64 + lane)
  int c0 = mask[MSRC(W0)];
  int c1 = mask[MSRC(W0 + 1)];
  #pragma unroll 4
  for (u32 k = 0; k < 16; ++k) {
    u64 bits = __ballot(c0 == 0);
    if (lane == 0) mp[W0 + k] = bits;
    c0 = c1;
    if (k + 2 < 16) c1 = mask[MSRC(W0 + k + 2)];
  }
  #undef MSRC
}

// ---------------------------------------------------------------------------
// Kernel 1: QKV projections, ASYNC-PIPELINED staging.
// A (x): fp32 global_load_lds into a32 dbuf (src pre-swizzled, chunk8/row),
//        issued 1 tile ahead, counted vmcnt(6); own-row convert -> abf bf16.
// B (W): pre-cast bf16, global_load_lds direct into bbf dbuf (chunk4/row).
// z=0: Q (scaled 1/8*log2e)  z=1: K  z=2: V -> VT transposed.
// grid (128, 4, 3), block 256.
// ---------------------------------------------------------------------------
__global__ __launch_bounds__(256, 2)
void qkv_proj(const float* __restrict__ xq, const float* __restrict__ xkv,
              const u16* __restrict__ Wbf,
              const float* __restrict__ bq, const float* __restrict__ bk,
              const float* __restrict__ bv,
              u16* __restrict__ Qo, u16* __restrict__ Ko, u16* __restrict__ VTo)
{
  __shared__ __align__(16) char smem[57344];
  char* a32 = smem;                     // 2 x 16384: fp32 A tiles
  char* bbf = smem + 32768;             // 2 x 8192:  bf16 B tiles
  char* abf = smem + 49152;             // 8192:      bf16 A tile

  const int t = threadIdx.x, lane = t & 63, w = t >> 6;
  const int z = blockIdx.z;
  const float* X  = (z == 0) ? xq : xkv;
  const u16*   W  = Wbf + (size_t)z * 262144;
  const float* Bv = (z == 0) ? bq : (z == 1 ? bk : bv);

  const int m0 = blockIdx.x * 128, n0 = blockIdx.y * 128;
  const int wr = w >> 1, wc = w & 1, g = lane >> 4, q15 = lane & 15;
  const int srow = t >> 1, shalf = t & 1;

  f32x4 acc[4][4];
  #pragma unroll
  for (int i = 0; i < 4; ++i)
    #pragma unroll
    for (int j = 0; j < 4; ++j) acc[i][j] = (f32x4){0.f, 0.f, 0.f, 0.f};

  // A staging: instr i, lane -> chunk c = w*256+i*64+lane; r=c>>3, s=c&7,
  // source col-chunk j = s ^ (r&7)  (16B chunks of 4 floats)
  const float* aSrc[4];
  int aDst[4];
  #pragma unroll
  for (int i = 0; i < 4; ++i) {
    int c = w * 256 + i * 64 + lane;
    int r = c >> 3, s = c & 7, j = s ^ (r & 7);
    aSrc[i] = X + (size_t)(m0 + r) * 512 + j * 4;
    aDst[i] = (w * 256 + i * 64) * 16;
  }
  // B staging: instr i, chunk c = i*256+w*64+lane; r=c>>2, s=c&3, j=s^(r&3)
  // (16B chunks of 8 bf16; 64B rows)
  const u16* bSrc[2];
  int bDst[2];
  #pragma unroll
  for (int i = 0; i < 2; ++i) {
    int c = i * 256 + w * 64 + lane;
    int r = c >> 2, s = c & 3, j = s ^ (r & 3);
    bSrc[i] = W + (size_t)(n0 + r) * 512 + j * 8;
    bDst[i] = (i * 256 + w * 64) * 16;
  }

  // prologue: stage tile 0 into buf 0
  #pragma unroll
  for (int i = 0; i < 4; ++i) gload_lds16(aSrc[i], a32 + aDst[i]);
  #pragma unroll
  for (int i = 0; i < 2; ++i) gload_lds16(bSrc[i], bbf + bDst[i]);
  asm volatile("" ::: "memory");

  const int wbyte = srow * 64;
  const int sw = (srow & 3) << 4;

  #pragma unroll 1
  for (int kt = 0; kt < 16; ++kt) {
    const int cur = kt & 1;
    if (kt + 1 < 16) {
      #pragma unroll
      for (int i = 0; i < 4; ++i) {
        aSrc[i] += 32;
        gload_lds16(aSrc[i], a32 + (cur ^ 1) * 16384 + aDst[i]);
      }
      #pragma unroll
      for (int i = 0; i < 2; ++i) {
        bSrc[i] += 32;
        gload_lds16(bSrc[i], bbf + (cur ^ 1) * 8192 + bDst[i]);
      }
      asm volatile("" ::: "memory");
      // stage(kt) done; 6 newer (stage kt+1) stay in flight
      asm volatile("s_waitcnt vmcnt(6)" ::: "memory");
    } else {
      asm volatile("s_waitcnt vmcnt(0)" ::: "memory");
    }
    asm volatile("s_waitcnt lgkmcnt(0)" ::: "memory");
    __builtin_amdgcn_sched_barrier(0);
    asm volatile("s_barrier" ::: "memory");   // frag reads(kt-1) done everywhere

    // ---- convert A(kt): own row fp32 -> cvtpk -> abf (same layout as ever)
    {
      const char* base = a32 + cur * 16384 + srow * 128;
      f32x4 av[4];
      #pragma unroll
      for (int jj = 0; jj < 4; ++jj) {
        int slot = (shalf * 4 + jj) ^ (srow & 7);
        av[jj] = *(const f32x4*)(base + slot * 16);
      }
      const float* pf = (const float*)av;
      #pragma unroll
      for (int half = 0; half < 2; ++half) {
        u32x4 wa;
        #pragma unroll
        for (int e2 = 0; e2 < 4; ++e2)
          wa[e2] = cvtpk(pf[half * 8 + 2 * e2], pf[half * 8 + 2 * e2 + 1]);
        *(u32x4*)(abf + wbyte + ((shalf * 32 + half * 16) ^ sw)) = wa;
      }
    }
    asm volatile("s_waitcnt lgkmcnt(0)" ::: "memory");
    __builtin_amdgcn_sched_barrier(0);
    asm volatile("s_barrier" ::: "memory");   // abf visible

    // ---- frags + MFMA ----
    s16x8 afr[4], bfr[4];
    #pragma unroll
    for (int mi = 0; mi < 4; ++mi) {
      int row = wr * 64 + mi * 16 + q15;
      afr[mi] = *(const s16x8*)(abf + row * 64 + ((g * 16) ^ ((row & 3) << 4)));
    }
    #pragma unroll
    for (int ni = 0; ni < 4; ++ni) {
      int row = wc * 64 + ni * 16 + q15;
      bfr[ni] = *(const s16x8*)(bbf + cur * 8192 + row * 64 + ((g * 16) ^ ((row & 3) << 4)));
    }
    #pragma unroll
    for (int mi = 0; mi < 4; ++mi)
      #pragma unroll
      for (int ni = 0; ni < 4; ++ni)
        acc[mi][ni] = mfma_bf16(afr[mi], bfr[ni], acc[mi][ni]);
  }

  float bias[4];
  #pragma unroll
  for (int ni = 0; ni < 4; ++ni) bias[ni] = Bv[n0 + wc * 64 + ni * 16 + q15];

  if (z < 2) {
    u16* Out = z ? Ko : Qo;
    const float scale = z ? 1.0f : 0.18033688011112042f;  // 1/8 * log2(e)
    #pragma unroll
    for (int mi = 0; mi < 4; ++mi)
      #pragma unroll
      for (int ni = 0; ni < 4; ++ni)
        #pragma unroll
        for (int r = 0; r < 4; r += 2) {
          int m = m0 + wr * 64 + mi * 16 + g * 4 + r;
          int n = n0 + wc * 64 + ni * 16 + q15;
          u32 pk = cvtpk((acc[mi][ni][r] + bias[ni]) * scale,
                         (acc[mi][ni][r + 1] + bias[ni]) * scale);
          Out[(size_t)m * 512 + n]       = (u16)pk;
          Out[(size_t)(m + 1) * 512 + n] = (u16)(pk >> 16);
        }
  } else {
    __syncthreads();                    // all frag reads done; reuse smem
    #pragma unroll
    for (int mi = 0; mi < 4; ++mi)
      #pragma unroll
      for (int ni = 0; ni < 4; ++ni)
        #pragma unroll
        for (int r = 0; r < 4; r += 2) {
          int ml = wr * 64 + mi * 16 + g * 4 + r;
          int nl = wc * 64 + ni * 16 + q15;
          *(u32*)(smem + nl * 272 + ml * 2) =
              cvtpk(acc[mi][ni][r] + bias[ni], acc[mi][ni][r + 1] + bias[ni]);
        }
    __syncthreads();
    const int b  = m0 >> 11;
    const int s0 = m0 & 2047;
    #pragma unroll
    for (int nn = 0; nn < 2; ++nn) {
      int n  = nn * 64 + (t >> 2);
      int q4 = t & 3;
      u16* dst = VTo + (size_t)(b * 512 + n0 + n) * 2048 + s0 + q4 * 32;
      #pragma unroll
      for (int jj = 0; jj < 4; ++jj)
        *(s16x8*)(dst + jj * 8) = *(const s16x8*)(smem + n * 272 + q4 * 64 + jj * 16);
    }
  }
}

// ---------------------------------------------------------------------------
// Kernel 2: fused flash attention — EXACT R7 form (measured 112 us):
// 4 waves x 32q, LDS K/V dbuf, counted vmcnt(5), two barriers, no setprio.
// No-max exp2 softmax; ones-MFMA row sums.
// grid.x = h + 8*b + 64*qt; block 256.
// ---------------------------------------------------------------------------
__global__ __launch_bounds__(256, 3)
void attn_fwd(const u16* __restrict__ Q, const u16* __restrict__ K,
              const u16* __restrict__ VT, const u64* __restrict__ MP,
              float* __restrict__ out)
{
  __shared__ __align__(16) char lds_k[2][8192];  // [kv 64][d 64] bf16, swizzled
  __shared__ __align__(16) char lds_v[2][8192];  // [d 64][kv 64] bf16, swizzled

  const int bid = blockIdx.x;
  const int h = bid & 7, b = (bid >> 3) & 7, qt = bid >> 6;
  const int t = threadIdx.x, lane = t & 63, w = t >> 6;
  const int l31 = lane & 31, hi = lane >> 5;
  const int qbase = qt * 128 + w * 32;
  const int swz = (l31 & 7) << 4;

  s16x8 qf[4];
  #pragma unroll
  for (int j = 0; j < 4; ++j)
    qf[j] = *(const s16x8*)(Q + (size_t)(b * 2048 + qbase + l31) * 512
                              + h * 64 + j * 16 + hi * 8);
  asm volatile("" ::: "memory");

  f32x16 o0 = {0.f,0.f,0.f,0.f,0.f,0.f,0.f,0.f,0.f,0.f,0.f,0.f,0.f,0.f,0.f,0.f};
  f32x16 o1 = o0, o2 = o0;
  const f32x16 ZZ = o0;
  const s16x8 onesf = {0x3F80,0x3F80,0x3F80,0x3F80,0x3F80,0x3F80,0x3F80,0x3F80};

  const int srow8 = lane >> 3, slot = lane & 7;
  const int rl0 = w * 16 + srow8, rl1 = rl0 + 8;

  const u16* kP0 = K + (size_t)(b * 2048 + rl0) * 512 + h * 64 + (slot ^ (rl0 & 7)) * 8;
  const u16* kP1 = K + (size_t)(b * 2048 + rl1) * 512 + h * 64 + (slot ^ (rl1 & 7)) * 8;
  const u16* vP0 = VT + (size_t)(b * 512 + h * 64 + rl0) * 2048 + (slot ^ (rl0 & 7)) * 8;
  const u16* vP1 = VT + (size_t)(b * 512 + h * 64 + rl1) * 2048 + (slot ^ (rl1 & 7)) * 8;
  const u64* mpP = MP + (size_t)b * 32 * 2048 + qbase + l31;

  gload_lds16(kP0, &lds_k[0][w * 2048]);
  gload_lds16(vP0, &lds_v[0][w * 2048]);
  gload_lds16(kP1, &lds_k[0][w * 2048 + 1024]);
  gload_lds16(vP1, &lds_v[0][w * 2048 + 1024]);
  asm volatile("" ::: "memory");
  u64 pm = *mpP;

  #pragma unroll 1
  for (int kt = 0; kt < 32; ++kt) {
    const int cur = kt & 1;
    const u64 kw = pm;
    if (kt + 1 < 32) {
      kP0 += 32768; kP1 += 32768; vP0 += 64; vP1 += 64; mpP += 2048;
      gload_lds16(kP0, &lds_k[cur ^ 1][w * 2048]);
      gload_lds16(vP0, &lds_v[cur ^ 1][w * 2048]);
      gload_lds16(kP1, &lds_k[cur ^ 1][w * 2048 + 1024]);
      gload_lds16(vP1, &lds_v[cur ^ 1][w * 2048 + 1024]);
      asm volatile("" ::: "memory");
      pm = mpP[0];
      // newer than {stage(kt), mask(kt)}: stage(kt+1)=4 + mask(kt+1)=1 = 5
      asm volatile("s_waitcnt vmcnt(5)" ::: "memory");
    } else {
      asm volatile("s_waitcnt vmcnt(0)" ::: "memory");
    }
    asm volatile("s_barrier" ::: "memory");

    // ---- S^T = K * Q^T over d=64 ----
    f32x16 p0 = ZZ, p1 = ZZ;
    #pragma unroll
    for (int j = 0; j < 4; ++j) {
      s16x8 a0 = *(const s16x8*)(&lds_k[cur][ l31       * 128 + ((j * 32 + hi * 16) ^ swz)]);
      s16x8 a1 = *(const s16x8*)(&lds_k[cur][(l31 + 32) * 128 + ((j * 32 + hi * 16) ^ swz)]);
      p0 = mfma32(a0, qf[j], p0);
      p1 = mfma32(a1, qf[j], p1);
    }

    // ---- masked exp2 -> packed bf16 words ----
    u64 kws = kw >> (hi * 4);
    u32 mm0 = (u32)kws, mm1 = (u32)(kws >> 32);
    u32 wds[16];
    #pragma unroll
    for (int t2 = 0; t2 < 2; ++t2) {
      const u32 mmw = t2 ? mm1 : mm0;
      #pragma unroll
      for (int q2 = 0; q2 < 8; ++q2) {
        const int bp = 8 * (q2 >> 1) + 2 * (q2 & 1);
        float s0v = t2 ? p1[2 * q2] : p0[2 * q2];
        float s1v = t2 ? p1[2 * q2 + 1] : p0[2 * q2 + 1];
        float e0 = EXP2(s0v), e1 = EXP2(s1v);
        u32 k0 = (u32)((int)(mmw << (31 - bp)) >> 31);
        u32 k1 = (u32)((int)(mmw << (30 - bp)) >> 31);
        e0 = __builtin_bit_cast(float, __builtin_bit_cast(u32, e0) & k0);
        e1 = __builtin_bit_cast(float, __builtin_bit_cast(u32, e1) & k1);
        wds[t2 * 8 + q2] = cvtpk(e0, e1);
      }
    }

    // ---- PV + ones-column row sums ----
    #pragma unroll
    for (int j = 0; j < 4; ++j) {
      const int ia = 2 * j, ib = 2 * j + 1;
      u32 wa0 = wds[(ia >> 2) * 8 + 2 * (ia & 3)];
      u32 wa1 = wds[(ia >> 2) * 8 + 2 * (ia & 3) + 1];
      u32 wb0 = wds[(ib >> 2) * 8 + 2 * (ib & 3)];
      u32 wb1 = wds[(ib >> 2) * 8 + 2 * (ib & 3) + 1];
      asm("v_permlane32_swap_b32 %0, %1" : "+v"(wa0), "+v"(wb0));
      asm("v_permlane32_swap_b32 %0, %1" : "+v"(wa1), "+v"(wb1));
      u32x4 aw = {wa0, wa1, wb0, wb1};
      s16x8 af = __builtin_bit_cast(s16x8, aw);
      s16x8 v0 = *(const s16x8*)(&lds_v[cur][ l31       * 128 + ((j * 32 + hi * 16) ^ swz)]);
      s16x8 v1 = *(const s16x8*)(&lds_v[cur][(l31 + 32) * 128 + ((j * 32 + hi * 16) ^ swz)]);
      o0 = mfma32(af, v0, o0);
      o1 = mfma32(af, v1, o1);
      o2 = mfma32(af, onesf, o2);
    }

    asm volatile("s_waitcnt lgkmcnt(0)" ::: "memory");
    __builtin_amdgcn_sched_barrier(0);
    asm volatile("s_barrier" ::: "memory");
  }

  #pragma unroll
  for (int reg = 0; reg < 16; ++reg) {
    const int ql = (reg & 3) + 8 * (reg >> 2) + 4 * hi;
    const float linv = 1.0f / o2[reg];
    float* po = out + (size_t)(b * 2048 + qbase + ql) * 512 + h * 64 + l31;
    po[0]  = o0[reg] * linv;
    po[32] = o1[reg] * linv;
  }
}

extern "C" void kernel_launch(void* const* d_in, const int* in_sizes, int n_in,
                              void* d_out, int out_size, void* d_ws, size_t ws_size,
                              hipStream_t stream) {
  const float* xq  = (const float*)d_in[0];
  const float* xkv = (const float*)d_in[1];
  const int*   msk = (const int*)d_in[2];
  const float* wq  = (const float*)d_in[3];
  const float* bq  = (const float*)d_in[4];
  const float* wk  = (const float*)d_in[5];
  const float* bk  = (const float*)d_in[6];
  const float* wv  = (const float*)d_in[7];
  const float* bv  = (const float*)d_in[8];

  u16* Qw  = (u16*)d_ws;                         // [16384][512] bf16 (x 0.1803)
  u16* Kw  = Qw + (size_t)16384 * 512;           // [16384][512] bf16
  u16* VT  = Kw + (size_t)16384 * 512;           // [4096][2048] bf16 (V^T)
  u64* MP  = (u64*)(VT + (size_t)4096 * 2048);   // [8][32][2048] packed keep bits
  u16* Wbf = (u16*)(MP + (size_t)8 * 32 * 2048); // [3][512][512] bf16 weights

  mask_pack<<<dim3(8384), 256, 0, stream>>>(msk, MP, wq, wk, wv, Wbf);
  qkv_proj<<<dim3(128, 4, 3), 256, 0, stream>>>(xq, xkv, Wbf, bq, bk, bv,
                                                Qw, Kw, VT);
  attn_fwd<<<dim3(1024), 256, 0, stream>>>(Qw, Kw, VT, MP, (float*)d_out);
}

// Round 12
// 197.717 us; speedup vs baseline: 1.5115x; 1.0127x over previous
//
#include <hip/hip_runtime.h>
#include <hip/hip_bf16.h>
#include <math.h>

typedef float  f32x4  __attribute__((ext_vector_type(4)));
typedef float  f32x16 __attribute__((ext_vector_type(16)));
typedef short  s16x8  __attribute__((ext_vector_type(8)));
typedef __bf16 bf16x8 __attribute__((ext_vector_type(8)));
typedef unsigned int u32;
typedef unsigned int u32x4 __attribute__((ext_vector_type(4)));
typedef unsigned short u16;
typedef unsigned long long u64;

#define DEVI static __device__ __forceinline__

#if defined(__has_builtin) && __has_builtin(__builtin_amdgcn_exp2f)
#define EXP2(x) __builtin_amdgcn_exp2f(x)
#else
#define EXP2(x) exp2f(x)
#endif

// one-instruction packed f32->bf16 RNE pair (v_cvt_pk_bf16_f32)
DEVI u32 cvtpk(float lo, float hi) {
  u32 r;
  asm("v_cvt_pk_bf16_f32 %0, %1, %2" : "=v"(r) : "v"(lo), "v"(hi));
  return r;
}

DEVI f32x4 mfma_bf16(s16x8 a, s16x8 b, f32x4 c) {
  return __builtin_amdgcn_mfma_f32_16x16x32_bf16(
      __builtin_bit_cast(bf16x8, a), __builtin_bit_cast(bf16x8, b), c, 0, 0, 0);
}

DEVI f32x16 mfma32(s16x8 a, s16x8 b, f32x16 c) {
  return __builtin_amdgcn_mfma_f32_32x32x16_bf16(
      __builtin_bit_cast(bf16x8, a), __builtin_bit_cast(bf16x8, b), c, 0, 0, 0);
}

DEVI void gload_lds16(const void* g, void* l) {
  __builtin_amdgcn_global_load_lds(
      (const __attribute__((address_space(1))) void*)g,
      (__attribute__((address_space(3))) void*)l, 16, 0, 0);
}

// ---------------------------------------------------------------------------
// Kernel 0: blocks < 8192: bit-pack KEEP bits (16 words/wave, 2-deep ahead).
//           blocks >= 8192 (192): cast W{q,k,v} fp32 -> bf16 into Wbf.
// ---------------------------------------------------------------------------
__global__ __launch_bounds__(256)
void mask_pack(const int* __restrict__ mask, u64* __restrict__ mp,
               const float* __restrict__ wq, const float* __restrict__ wk,
               const float* __restrict__ wv, u16* __restrict__ Wbf) {
  const int t = threadIdx.x, lane = t & 63;
  if (blockIdx.x >= 8192) {             // ---- W cast: 192 blocks x 4096 elems
    const u32 blk = blockIdx.x - 8192;
    const u32 g0 = blk * 4096 + (u32)t * 16;
    const u32 mtx = g0 >> 18;           // 64 blocks per matrix
    const float* src = (mtx == 0) ? wq : (mtx == 1 ? wk : wv);
    const u32 idx = g0 & 262143u;
    #pragma unroll
    for (int i = 0; i < 2; ++i) {
      f32x4 v0 = *(const f32x4*)(src + idx + i * 8);
      f32x4 v1 = *(const f32x4*)(src + idx + i * 8 + 4);
      u32x4 pk;
      pk[0] = cvtpk(v0[0], v0[1]); pk[1] = cvtpk(v0[2], v0[3]);
      pk[2] = cvtpk(v1[0], v1[1]); pk[3] = cvtpk(v1[2], v1[3]);
      *(u32x4*)(Wbf + (size_t)mtx * 262144 + idx + i * 8) = pk;
    }
    return;
  }
  const u32 gw = blockIdx.x * 4 + (t >> 6);
  const u32 W0 = gw * 16;
  #define MSRC(W) ((((size_t)((W) >> 16) * 2048 + ((W) & 2047u)) * 2048) \
                   + (((W) >> 11) & 31u) * 64 + lane)
  int c0 = mask[MSRC(W0)];
  int c1 = mask[MSRC(W0 + 1)];
  #pragma unroll 4
  for (u32 k = 0; k < 16; ++k) {
    u64 bits = __ballot(c0 == 0);
    if (lane == 0) mp[W0 + k] = bits;
    c0 = c1;
    if (k + 2 < 16) c1 = mask[MSRC(W0 + k + 2)];
  }
  #undef MSRC
}

// ---------------------------------------------------------------------------
// Kernel 1: QKV projections, ASYNC-PIPELINED staging (R11 form, frozen).
// ---------------------------------------------------------------------------
__global__ __launch_bounds__(256, 2)
void qkv_proj(const float* __restrict__ xq, const float* __restrict__ xkv,
              const u16* __restrict__ Wbf,
              const float* __restrict__ bq, const float* __restrict__ bk,
              const float* __restrict__ bv,
              u16* __restrict__ Qo, u16* __restrict__ Ko, u16* __restrict__ VTo)
{
  __shared__ __align__(16) char smem[57344];
  char* a32 = smem;                     // 2 x 16384: fp32 A tiles
  char* bbf = smem + 32768;             // 2 x 8192:  bf16 B tiles
  char* abf = smem + 49152;             // 8192:      bf16 A tile

  const int t = threadIdx.x, lane = t & 63, w = t >> 6;
  const int z = blockIdx.z;
  const float* X  = (z == 0) ? xq : xkv;
  const u16*   W  = Wbf + (size_t)z * 262144;
  const float* Bv = (z == 0) ? bq : (z == 1 ? bk : bv);

  const int m0 = blockIdx.x * 128, n0 = blockIdx.y * 128;
  const int wr = w >> 1, wc = w & 1, g = lane >> 4, q15 = lane & 15;
  const int srow = t >> 1, shalf = t & 1;

  f32x4 acc[4][4];
  #pragma unroll
  for (int i = 0; i < 4; ++i)
    #pragma unroll
    for (int j = 0; j < 4; ++j) acc[i][j] = (f32x4){0.f, 0.f, 0.f, 0.f};

  const float* aSrc[4];
  int aDst[4];
  #pragma unroll
  for (int i = 0; i < 4; ++i) {
    int c = w * 256 + i * 64 + lane;
    int r = c >> 3, s = c & 7, j = s ^ (r & 7);
    aSrc[i] = X + (size_t)(m0 + r) * 512 + j * 4;
    aDst[i] = (w * 256 + i * 64) * 16;
  }
  const u16* bSrc[2];
  int bDst[2];
  #pragma unroll
  for (int i = 0; i < 2; ++i) {
    int c = i * 256 + w * 64 + lane;
    int r = c >> 2, s = c & 3, j = s ^ (r & 3);
    bSrc[i] = W + (size_t)(n0 + r) * 512 + j * 8;
    bDst[i] = (i * 256 + w * 64) * 16;
  }

  #pragma unroll
  for (int i = 0; i < 4; ++i) gload_lds16(aSrc[i], a32 + aDst[i]);
  #pragma unroll
  for (int i = 0; i < 2; ++i) gload_lds16(bSrc[i], bbf + bDst[i]);
  asm volatile("" ::: "memory");

  const int wbyte = srow * 64;
  const int sw = (srow & 3) << 4;

  #pragma unroll 1
  for (int kt = 0; kt < 16; ++kt) {
    const int cur = kt & 1;
    if (kt + 1 < 16) {
      #pragma unroll
      for (int i = 0; i < 4; ++i) {
        aSrc[i] += 32;
        gload_lds16(aSrc[i], a32 + (cur ^ 1) * 16384 + aDst[i]);
      }
      #pragma unroll
      for (int i = 0; i < 2; ++i) {
        bSrc[i] += 32;
        gload_lds16(bSrc[i], bbf + (cur ^ 1) * 8192 + bDst[i]);
      }
      asm volatile("" ::: "memory");
      asm volatile("s_waitcnt vmcnt(6)" ::: "memory");
    } else {
      asm volatile("s_waitcnt vmcnt(0)" ::: "memory");
    }
    asm volatile("s_waitcnt lgkmcnt(0)" ::: "memory");
    __builtin_amdgcn_sched_barrier(0);
    asm volatile("s_barrier" ::: "memory");

    {
      const char* base = a32 + cur * 16384 + srow * 128;
      f32x4 av[4];
      #pragma unroll
      for (int jj = 0; jj < 4; ++jj) {
        int slot = (shalf * 4 + jj) ^ (srow & 7);
        av[jj] = *(const f32x4*)(base + slot * 16);
      }
      const float* pf = (const float*)av;
      #pragma unroll
      for (int half = 0; half < 2; ++half) {
        u32x4 wa;
        #pragma unroll
        for (int e2 = 0; e2 < 4; ++e2)
          wa[e2] = cvtpk(pf[half * 8 + 2 * e2], pf[half * 8 + 2 * e2 + 1]);
        *(u32x4*)(abf + wbyte + ((shalf * 32 + half * 16) ^ sw)) = wa;
      }
    }
    asm volatile("s_waitcnt lgkmcnt(0)" ::: "memory");
    __builtin_amdgcn_sched_barrier(0);
    asm volatile("s_barrier" ::: "memory");

    s16x8 afr[4], bfr[4];
    #pragma unroll
    for (int mi = 0; mi < 4; ++mi) {
      int row = wr * 64 + mi * 16 + q15;
      afr[mi] = *(const s16x8*)(abf + row * 64 + ((g * 16) ^ ((row & 3) << 4)));
    }
    #pragma unroll
    for (int ni = 0; ni < 4; ++ni) {
      int row = wc * 64 + ni * 16 + q15;
      bfr[ni] = *(const s16x8*)(bbf + cur * 8192 + row * 64 + ((g * 16) ^ ((row & 3) << 4)));
    }
    #pragma unroll
    for (int mi = 0; mi < 4; ++mi)
      #pragma unroll
      for (int ni = 0; ni < 4; ++ni)
        acc[mi][ni] = mfma_bf16(afr[mi], bfr[ni], acc[mi][ni]);
  }

  float bias[4];
  #pragma unroll
  for (int ni = 0; ni < 4; ++ni) bias[ni] = Bv[n0 + wc * 64 + ni * 16 + q15];

  if (z < 2) {
    u16* Out = z ? Ko : Qo;
    const float scale = z ? 1.0f : 0.18033688011112042f;  // 1/8 * log2(e)
    #pragma unroll
    for (int mi = 0; mi < 4; ++mi)
      #pragma unroll
      for (int ni = 0; ni < 4; ++ni)
        #pragma unroll
        for (int r = 0; r < 4; r += 2) {
          int m = m0 + wr * 64 + mi * 16 + g * 4 + r;
          int n = n0 + wc * 64 + ni * 16 + q15;
          u32 pk = cvtpk((acc[mi][ni][r] + bias[ni]) * scale,
                         (acc[mi][ni][r + 1] + bias[ni]) * scale);
          Out[(size_t)m * 512 + n]       = (u16)pk;
          Out[(size_t)(m + 1) * 512 + n] = (u16)(pk >> 16);
        }
  } else {
    __syncthreads();
    #pragma unroll
    for (int mi = 0; mi < 4; ++mi)
      #pragma unroll
      for (int ni = 0; ni < 4; ++ni)
        #pragma unroll
        for (int r = 0; r < 4; r += 2) {
          int ml = wr * 64 + mi * 16 + g * 4 + r;
          int nl = wc * 64 + ni * 16 + q15;
          *(u32*)(smem + nl * 272 + ml * 2) =
              cvtpk(acc[mi][ni][r] + bias[ni], acc[mi][ni][r + 1] + bias[ni]);
        }
    __syncthreads();
    const int b  = m0 >> 11;
    const int s0 = m0 & 2047;
    #pragma unroll
    for (int nn = 0; nn < 2; ++nn) {
      int n  = nn * 64 + (t >> 2);
      int q4 = t & 3;
      u16* dst = VTo + (size_t)(b * 512 + n0 + n) * 2048 + s0 + q4 * 32;
      #pragma unroll
      for (int jj = 0; jj < 4; ++jj)
        *(s16x8*)(dst + jj * 8) = *(const s16x8*)(smem + n * 272 + q4 * 64 + jj * 16);
    }
  }
}

// ---------------------------------------------------------------------------
// Kernel 2: fused flash attention, KVBLK=128: R7 schedule (stage-before-wait,
// counted vmcnt, two barriers) but TWO 64-kv halves per barrier window ->
// half the sync overhead, and half-B's QK MFMAs can overlap half-A's exp
// VALU inside the barrier-free region.  LDS 64 KB, 2 blocks/CU.
// grid.x = h + 8*b + 64*qt; block 256 = 4 waves x 32 q-rows.
// ---------------------------------------------------------------------------
__global__ __launch_bounds__(256, 2)
void attn_fwd(const u16* __restrict__ Q, const u16* __restrict__ K,
              const u16* __restrict__ VT, const u64* __restrict__ MP,
              float* __restrict__ out)
{
  __shared__ __align__(16) char lds_k[2][16384];    // [kv 128][d 64] bf16
  __shared__ __align__(16) char lds_v[2][2][8192];  // [buf][kvhalf][d64][kv64]

  const int bid = blockIdx.x;
  const int hh = bid & 7, b = (bid >> 3) & 7, qt = bid >> 6;
  const int t = threadIdx.x, lane = t & 63, w = t >> 6;
  const int l31 = lane & 31, hi = lane >> 5;
  const int qbase = qt * 128 + w * 32;
  const int swz = (l31 & 7) << 4;

  // Q B-frags (pre-scaled by 0.125*log2e): col=q=l31, k(d) = j*16 + 8*hi + e
  s16x8 qf[4];
  #pragma unroll
  for (int j = 0; j < 4; ++j)
    qf[j] = *(const s16x8*)(Q + (size_t)(b * 2048 + qbase + l31) * 512
                              + hh * 64 + j * 16 + hi * 8);
  asm volatile("" ::: "memory");

  f32x16 o0 = {0.f,0.f,0.f,0.f,0.f,0.f,0.f,0.f,0.f,0.f,0.f,0.f,0.f,0.f,0.f,0.f};
  f32x16 o1 = o0, o2 = o0;
  const f32x16 ZZ = o0;
  const s16x8 onesf = {0x3F80,0x3F80,0x3F80,0x3F80,0x3F80,0x3F80,0x3F80,0x3F80};

  const int srow8 = lane >> 3, slot = lane & 7;

  // K staging: instr i=0..3, rows rl = w*32 + i*8 + srow8 (0..127)
  const u16* kP[4];
  int kD[4];
  #pragma unroll
  for (int i = 0; i < 4; ++i) {
    int rl = w * 32 + i * 8 + srow8;
    kP[i] = K + (size_t)(b * 2048 + rl) * 512 + hh * 64 + (slot ^ (rl & 7)) * 8;
    kD[i] = (w * 32 + i * 8) * 128;
  }
  // V staging: instr i=0..1 per half, d = w*16 + i*8 + srow8 (0..63)
  const u16* vP[2];
  int vD[2];
  #pragma unroll
  for (int i = 0; i < 2; ++i) {
    int d = w * 16 + i * 8 + srow8;
    vP[i] = VT + (size_t)(b * 512 + hh * 64 + d) * 2048 + (slot ^ (d & 7)) * 8;
    vD[i] = (w * 16 + i * 8) * 128;
  }
  const u64* mpP = MP + (size_t)b * 32 * 2048 + qbase + l31;

  // prologue: stage tile 0 (kv 0..127) into buf 0; prefetch mask words 0,1
  #pragma unroll
  for (int i = 0; i < 4; ++i) gload_lds16(kP[i], &lds_k[0][kD[i]]);
  #pragma unroll
  for (int hf = 0; hf < 2; ++hf)
    #pragma unroll
    for (int i = 0; i < 2; ++i)
      gload_lds16(vP[i] + hf * 64, &lds_v[0][hf][vD[i]]);
  asm volatile("" ::: "memory");
  u64 pm0 = mpP[0], pm1 = mpP[2048];

  // one 64-kv half: QK (8 mfma) -> masked exp2/pack -> PV + ones (12 mfma)
#define HALF(KB, VB, KW) do {                                                  \
    f32x16 p0 = ZZ, p1 = ZZ;                                                   \
    _Pragma("unroll")                                                          \
    for (int j = 0; j < 4; ++j) {                                              \
      s16x8 a0 = *(const s16x8*)((KB) + l31 * 128        + ((j * 32 + hi * 16) ^ swz)); \
      s16x8 a1 = *(const s16x8*)((KB) + (l31 + 32) * 128 + ((j * 32 + hi * 16) ^ swz)); \
      p0 = mfma32(a0, qf[j], p0);                                              \
      p1 = mfma32(a1, qf[j], p1);                                              \
    }                                                                          \
    u64 kws = (KW) >> (hi * 4);                                                \
    u32 mm0 = (u32)kws, mm1 = (u32)(kws >> 32);                                \
    u32 wds[16];                                                               \
    _Pragma("unroll")                                                          \
    for (int t2 = 0; t2 < 2; ++t2) {                                           \
      const u32 mmw = t2 ? mm1 : mm0;                                          \
      _Pragma("unroll")                                                        \
      for (int q2 = 0; q2 < 8; ++q2) {                                         \
        const int bp = 8 * (q2 >> 1) + 2 * (q2 & 1);                           \
        float s0v = t2 ? p1[2 * q2] : p0[2 * q2];                              \
        float s1v = t2 ? p1[2 * q2 + 1] : p0[2 * q2 + 1];                      \
        float e0 = EXP2(s0v), e1 = EXP2(s1v);                                  \
        u32 k0 = (u32)((int)(mmw << (31 - bp)) >> 31);                         \
        u32 k1 = (u32)((int)(mmw << (30 - bp)) >> 31);                         \
        e0 = __builtin_bit_cast(float, __builtin_bit_cast(u32, e0) & k0);      \
        e1 = __builtin_bit_cast(float, __builtin_bit_cast(u32, e1) & k1);      \
        wds[t2 * 8 + q2] = cvtpk(e0, e1);                                      \
      }                                                                        \
    }                                                                          \
    _Pragma("unroll")                                                          \
    for (int j = 0; j < 4; ++j) {                                              \
      const int ia = 2 * j, ib = 2 * j + 1;                                    \
      u32 wa0 = wds[(ia >> 2) * 8 + 2 * (ia & 3)];                             \
      u32 wa1 = wds[(ia >> 2) * 8 + 2 * (ia & 3) + 1];                         \
      u32 wb0 = wds[(ib >> 2) * 8 + 2 * (ib & 3)];                             \
      u32 wb1 = wds[(ib >> 2) * 8 + 2 * (ib & 3) + 1];                         \
      asm("v_permlane32_swap_b32 %0, %1" : "+v"(wa0), "+v"(wb0));              \
      asm("v_permlane32_swap_b32 %0, %1" : "+v"(wa1), "+v"(wb1));              \
      u32x4 aw = {wa0, wa1, wb0, wb1};                                         \
      s16x8 af = __builtin_bit_cast(s16x8, aw);                                \
      s16x8 v0 = *(const s16x8*)((VB) + l31 * 128        + ((j * 32 + hi * 16) ^ swz)); \
      s16x8 v1 = *(const s16x8*)((VB) + (l31 + 32) * 128 + ((j * 32 + hi * 16) ^ swz)); \
      o0 = mfma32(af, v0, o0);                                                 \
      o1 = mfma32(af, v1, o1);                                                 \
      o2 = mfma32(af, onesf, o2);                                              \
    }                                                                          \
  } while (0)

  #pragma unroll 1
  for (int kt = 0; kt < 16; ++kt) {
    const int cur = kt & 1;
    const u64 kwA = pm0, kwB = pm1;
    if (kt + 1 < 16) {
      #pragma unroll
      for (int i = 0; i < 4; ++i) kP[i] += 65536;
      #pragma unroll
      for (int i = 0; i < 2; ++i) vP[i] += 128;
      mpP += 4096;
      #pragma unroll
      for (int i = 0; i < 4; ++i) gload_lds16(kP[i], &lds_k[cur ^ 1][kD[i]]);
      #pragma unroll
      for (int hf = 0; hf < 2; ++hf)
        #pragma unroll
        for (int i = 0; i < 2; ++i)
          gload_lds16(vP[i] + hf * 64, &lds_v[cur ^ 1][hf][vD[i]]);
      asm volatile("" ::: "memory");
      pm0 = mpP[0]; pm1 = mpP[2048];
      // newer than stage(kt): stage(kt+1)=8 + mask(kt+1)=2 = 10
      asm volatile("s_waitcnt vmcnt(10)" ::: "memory");
    } else {
      asm volatile("s_waitcnt vmcnt(0)" ::: "memory");
    }
    asm volatile("s_barrier" ::: "memory");

    HALF(&lds_k[cur][0],    &lds_v[cur][0][0], kwA);
    HALF(&lds_k[cur][8192], &lds_v[cur][1][0], kwB);

    asm volatile("s_waitcnt lgkmcnt(0)" ::: "memory");
    __builtin_amdgcn_sched_barrier(0);
    asm volatile("s_barrier" ::: "memory");
  }
#undef HALF

  // ---- epilogue: o2[reg] IS the row denominator for o0/o1[reg] ----
  #pragma unroll
  for (int reg = 0; reg < 16; ++reg) {
    const int ql = (reg & 3) + 8 * (reg >> 2) + 4 * hi;
    const float linv = 1.0f / o2[reg];
    float* po = out + (size_t)(b * 2048 + qbase + ql) * 512 + hh * 64 + l31;
    po[0]  = o0[reg] * linv;
    po[32] = o1[reg] * linv;
  }
}

extern "C" void kernel_launch(void* const* d_in, const int* in_sizes, int n_in,
                              void* d_out, int out_size, void* d_ws, size_t ws_size,
                              hipStream_t stream) {
  const float* xq  = (const float*)d_in[0];
  const float* xkv = (const float*)d_in[1];
  const int*   msk = (const int*)d_in[2];
  const float* wq  = (const float*)d_in[3];
  const float* bq  = (const float*)d_in[4];
  const float* wk  = (const float*)d_in[5];
  const float* bk  = (const float*)d_in[6];
  const float* wv  = (const float*)d_in[7];
  const float* bv  = (const float*)d_in[8];

  u16* Qw  = (u16*)d_ws;                         // [16384][512] bf16 (x 0.1803)
  u16* Kw  = Qw + (size_t)16384 * 512;           // [16384][512] bf16
  u16* VT  = Kw + (size_t)16384 * 512;           // [4096][2048] bf16 (V^T)
  u64* MP  = (u64*)(VT + (size_t)4096 * 2048);   // [8][32][2048] packed keep bits
  u16* Wbf = (u16*)(MP + (size_t)8 * 32 * 2048); // [3][512][512] bf16 weights

  mask_pack<<<dim3(8384), 256, 0, stream>>>(msk, MP, wq, wk, wv, Wbf);
  qkv_proj<<<dim3(128, 4, 3), 256, 0, stream>>>(xq, xkv, Wbf, bq, bk, bv,
                                                Qw, Kw, VT);
  attn_fwd<<<dim3(1024), 256, 0, stream>>>(Qw, Kw, VT, MP, (float*)d_out);
}